// Round 5
// baseline (1389.230 us; speedup 1.0000x reference)
//
#include <hip/hip_runtime.h>
#include <cfloat>

// ClDiceLoss (B=2, C=1, 192^3) fp32 — register-streaming soft-skeletonize.
//
// Round-12. Round-11 tell fired: VGPR stayed 60 -> sched_barrier(0) can't
// pin the prefetch ring (collapse crosses basic-block bounds); per-step
// serial chain (~1450cy: exposed load latency + 8 bpermutes + min/max
// trees) is amortized over only 3 waves/SIMD because CZ=48 yields exactly
// 16 windows x 192 rows = 3072 waves. This round doubles TLP instead:
//   CZ 48->24 WITH the bijective XCD swizzle kept. Round-9's fetch
//   explosion at CZ=24 was placement (no swizzle, windows scattered over
//   8 incoherent L2s), not capacity: active set/window ~6 planes ~0.9MB;
//   4 whole windows/XCD ~3.5MB < 4MB L2. Grid 1536 = exactly 6 blocks/CU,
//   launch_bounds(256,6) (VGPR cap 85 >= 60 used).
// Falsification tell: FETCH > 150MB -> L2-capacity model wrong; revert to
// CZ=48 and pin loads via inline asm instead.
//
// Kept: ring-5 / 2-ahead issue order (harmless), sched_barrier pin,
// dwordx3 loads/stores, separable 3x3 max (8 bpermutes/step), XCD swizzle.
// Decomposition: W = 192 = 64 lanes x 3 cols -> one wave spans full x;
// wave owns y-row gy; rows gy-2..gy+2 per plane; ring-5 z-stream.
// Boundaries: x edge == wave edge -> cndmask pads; y edge -> -FLT_MAX M
// rows; z edge -> zlo/zhi guards; clamped dup loads are min-neutral.
// No __shared__, no __syncthreads in skel_iter.

constexpr int D = 192, H = 192, W = 192, B = 2;
constexpr int HW = H * W;
constexpr int VOL = D * HW;
constexpr int CZ = 24;              // z-chunk (divides D)
constexpr int NCH = D / CZ;         // 8 chunks
constexpr int WPB = 4;              // waves (y-strips) per block
constexpr int NGY = H / WPB;        // 48
constexpr int STEPS = 30;           // 5-phase ring; emit window s in [3,CZ+2]
constexpr int NPART = B * NCH * H;  // 3072 per chain

struct F3 { float x, y, z; };       // 12B -> global_load_dwordx3

__device__ __forceinline__ float min3f(float a, float b, float c) {
  return fminf(fminf(a, b), c);
}
__device__ __forceinline__ float max3f(float a, float b, float c) {
  return fmaxf(fmaxf(a, b), c);
}

__global__ __launch_bounds__(256, 6) void skel_iter(
    const float* __restrict__ srcA, float* __restrict__ dstA,
    const float* __restrict__ othA, double* __restrict__ partA,
    const float* __restrict__ srcB, float* __restrict__ dstB,
    const float* __restrict__ othB, double* __restrict__ partB,
    int last) {
  const int tid = threadIdx.x;
  const int lane = tid & 63;
  const int wv = tid >> 6;

  // ---- XCD-locality swizzle (bijective: nwg % 8 == 0) ----
  // Each XCD receives a contiguous run of remapped ids = whole
  // (chunk,b,chain) windows with all 48 gy-groups -> halo re-reads are
  // local-L2 hits (~4 windows x ~0.9MB active < 4MB L2/XCD).
  const int nwg = gridDim.x * gridDim.y * gridDim.z;
  int wid = blockIdx.x + gridDim.x * (blockIdx.y + gridDim.y * blockIdx.z);
  wid = (wid & 7) * (nwg >> 3) + (wid >> 3);
  const int gyg = wid % NGY;
  const int combo = wid / NGY;
  const int chunk = combo % NCH;
  const int bz = combo / NCH;
  const int b = bz % B;
  const int chain = bz / B;

  const int gy = gyg * WPB + wv;            // strip row 0..191

  const float* __restrict__ vs = (chain ? srcB : srcA) + (size_t)b * VOL;
  float* __restrict__ vd = (chain ? dstB : dstA) + (size_t)b * VOL;
  const float* __restrict__ vo = (chain ? othB : othA) + (size_t)b * VOL;
  double* __restrict__ part = chain ? partB : partA;

  const int z0 = chunk * CZ;
  const int c0 = 3 * lane;

  // Row offsets (z-invariant), rows gy-2..gy+2 clamped (dup is min-neutral;
  // out-of-volume M rows masked below).
  int rb[5];
  #pragma unroll
  for (int r = 0; r < 5; ++r) rb[r] = min(max(gy - 2 + r, 0), H - 1) * W + c0;
  const bool ytop = (gy == 0), ybot = (gy == H - 1);
  const bool l0 = (lane == 0), l63 = (lane == 63);

  // Register state. Ring slot of plane q is (q - z0) mod 5; all slot
  // indices below are compile-time via the 5-phase unroll.
  float xa[5][5][3];     // x plane ring
  float Mprev[3];        // M(z-2), center row (for out)
  float h1[3], h2[3];    // hxy(z-2), hxy(z-3)
  float sp = 0.0f, ss = 0.0f;

  // Prologue: z0-2 -> slot 3, z0-1 -> slot 4, z0 -> slot 0.
  {
    const float* ps = vs + (size_t)max(z0 - 2, 0) * HW;
    #pragma unroll
    for (int r = 0; r < 5; ++r) {
      const F3 v = *(const F3*)(ps + rb[r]);
      xa[3][r][0] = v.x; xa[3][r][1] = v.y; xa[3][r][2] = v.z;
    }
    ps = vs + (size_t)max(z0 - 1, 0) * HW;
    #pragma unroll
    for (int r = 0; r < 5; ++r) {
      const F3 v = *(const F3*)(ps + rb[r]);
      xa[4][r][0] = v.x; xa[4][r][1] = v.y; xa[4][r][2] = v.z;
    }
    ps = vs + (size_t)z0 * HW;
    #pragma unroll
    for (int r = 0; r < 5; ++r) {
      const F3 v = *(const F3*)(ps + rb[r]);
      xa[0][r][0] = v.x; xa[0][r][1] = v.y; xa[0][r][2] = v.z;
    }
  }

  #pragma unroll 1
  for (int s5 = 0; s5 < STEPS; s5 += 5) {
    #pragma unroll
    for (int p = 0; p < 5; ++p) {
      const int s = s5 + p;
      const int z = z0 - 1 + s;                 // pipeline front
      const int LD  = (p + 1) % 5;              // plane z+2 (load target)
      const int SM2 = (p + 2) % 5;              // plane z-2
      const int SM1 = (p + 3) % 5;              // plane z-1 (M center)
      const int SC  = (p + 4) % 5;              // plane z

      // Issue plane z+2 (consumed 2 phases later).
      {
        const int zc = min(z + 2, D - 1);
        const float* ps = vs + (size_t)zc * HW;
        #pragma unroll
        for (int r = 0; r < 5; ++r) {
          const F3 v = *(const F3*)(ps + rb[r]);
          xa[LD][r][0] = v.x; xa[LD][r][1] = v.y; xa[LD][r][2] = v.z;
        }
      }
      // Weight row for the fused reduction (last iteration only).
      const int zo = z - 2;
      const bool emit = (s >= 3) && (s <= CZ + 2);
      float w0 = 0.f, w1 = 0.f, w2 = 0.f;
      if (last && emit) {
        const F3 wv3 = *(const F3*)(vo + (size_t)zo * HW + rb[2]);
        w0 = wv3.x; w1 = wv3.y; w2 = wv3.z;
      }
      __builtin_amdgcn_sched_barrier(0);

      // ---- M(z-1): 7-pt cross min, rows gy-1..gy+1 (M rows 0..2) ----
      float xl[3], xr[3];
      #pragma unroll
      for (int r = 0; r < 3; ++r) {
        xl[r] = __shfl_up(xa[SM1][r + 1][2], 1, 64);    // col 3l-1
        xr[r] = __shfl_down(xa[SM1][r + 1][0], 1, 64);  // col 3l+3
        if (l0) xl[r] = FLT_MAX;    // x = -1  -> +inf pad (min-neutral)
        if (l63) xr[r] = FLT_MAX;   // x = 192 -> +inf pad
      }
      float Mc[3][3];
      #pragma unroll
      for (int r = 0; r < 3; ++r) {
        #pragma unroll
        for (int c = 0; c < 3; ++c) {
          const float le = (c == 0) ? xl[r] : xa[SM1][r + 1][c - 1];
          const float ri = (c == 2) ? xr[r] : xa[SM1][r + 1][c + 1];
          float v = min3f(xa[SM1][r + 1][c], le, ri);
          v = min3f(v, xa[SM1][r][c], xa[SM1][r + 2][c]);      // y+-1
          v = min3f(v, xa[SM2][r + 1][c], xa[SC][r + 1][c]);   // z+-1
          Mc[r][c] = v;
        }
      }
      // Out-of-volume M rows -> -inf (exact reduce_window -inf-pad for P).
      if (ytop) { Mc[0][0] = Mc[0][1] = Mc[0][2] = -FLT_MAX; }
      if (ybot) { Mc[2][0] = Mc[2][1] = Mc[2][2] = -FLT_MAX; }

      // ---- hxy(z-1): separable 3x3 max — row-max, then 2 shfls ----
      float rm[3];
      #pragma unroll
      for (int c = 0; c < 3; ++c) rm[c] = max3f(Mc[0][c], Mc[1][c], Mc[2][c]);
      float ml = __shfl_up(rm[2], 1, 64);
      float mr = __shfl_down(rm[0], 1, 64);
      if (l0) ml = -FLT_MAX;
      if (l63) mr = -FLT_MAX;
      float h0c[3];
      h0c[0] = max3f(ml, rm[0], rm[1]);
      h0c[1] = max3f(rm[0], rm[1], rm[2]);
      h0c[2] = max3f(rm[1], rm[2], mr);

      // ---- out(z-2) = relu(x - relu(P - M)) ----
      if (emit) {
        const bool zlo = (zo > 0), zhi = (zo < D - 1);
        float o[3];
        #pragma unroll
        for (int c = 0; c < 3; ++c) {
          float P = h1[c];
          if (zlo) P = fmaxf(P, h2[c]);
          if (zhi) P = fmaxf(P, h0c[c]);
          const float contour = fmaxf(P - Mprev[c], 0.0f);
          o[c] = fmaxf(xa[SM2][2][c] - contour, 0.0f);
        }
        if (last) {
          sp += o[0] * w0 + o[1] * w1 + o[2] * w2;
          ss += o[0] + o[1] + o[2];
        } else {
          *(F3*)(vd + (size_t)zo * HW + rb[2]) = {o[0], o[1], o[2]};
        }
      }

      // Ring advance (static names; compiler renames across phases).
      #pragma unroll
      for (int c = 0; c < 3; ++c) {
        h2[c] = h1[c];
        h1[c] = h0c[c];
        Mprev[c] = Mc[1][c];
      }
    }
  }

  if (last) {
    #pragma unroll
    for (int off = 32; off > 0; off >>= 1) {
      sp += __shfl_down(sp, off, 64);
      ss += __shfl_down(ss, off, 64);
    }
    if (lane == 0) {
      const int lin = (b * NCH + chunk) * H + gy;
      part[2 * lin] = (double)sp;
      part[2 * lin + 1] = (double)ss;
    }
  }
}

__global__ void finalize_kernel(const double* __restrict__ pa,
                                const double* __restrict__ pb,
                                float* __restrict__ out, int npart) {
  __shared__ double red[4][4];
  double s[4] = {0, 0, 0, 0};
  for (int i = threadIdx.x; i < npart; i += 256) {
    s[0] += pa[2 * i];
    s[1] += pa[2 * i + 1];
    s[2] += pb[2 * i];
    s[3] += pb[2 * i + 1];
  }
  #pragma unroll
  for (int off = 32; off > 0; off >>= 1)
    #pragma unroll
    for (int j = 0; j < 4; ++j) s[j] += __shfl_down(s[j], off, 64);
  const int wave = threadIdx.x >> 6, lane = threadIdx.x & 63;
  if (lane == 0)
    for (int j = 0; j < 4; ++j) red[j][wave] = s[j];
  __syncthreads();
  if (threadIdx.x == 0) {
    double t[4];
    for (int j = 0; j < 4; ++j)
      t[j] = red[j][0] + red[j][1] + red[j][2] + red[j][3];
    const double recall = (t[0] + 1e-12) / (t[1] + 1e-12);
    const double accv = (t[2] + 1e-12) / (t[3] + 1e-12);
    const double cldice = 2.0 * recall * accv / (recall + accv);
    out[0] = (float)(1.0 - cldice);
  }
}

extern "C" void kernel_launch(void* const* d_in, const int* in_sizes, int n_in,
                              void* d_out, int out_size, void* d_ws, size_t ws_size,
                              hipStream_t stream) {
  const float* pred = (const float*)d_in[0];
  const float* target = (const float*)d_in[1];
  float* out = (float*)d_out;
  const size_t NT = (size_t)VOL * B;

  const dim3 blk(256, 1, 1);
  const size_t need_merged = 4 * NT * sizeof(float) + 4 * NPART * sizeof(double);

  if (ws_size >= need_merged) {
    float* a0 = (float*)d_ws;
    float* a1 = a0 + NT;
    float* c0 = a1 + NT;
    float* c1 = c0 + NT;
    double* pA = (double*)(c1 + NT);
    double* pB = pA + 2 * NPART;
    const dim3 grd(NGY, NCH, 2 * B);   // 1536 blocks = exactly 6/CU
    skel_iter<<<grd, blk, 0, stream>>>(target, a0, pred, pA, pred, c0, target, pB, 0);
    skel_iter<<<grd, blk, 0, stream>>>(a0, a1, pred, pA, c0, c1, target, pB, 0);
    skel_iter<<<grd, blk, 0, stream>>>(a1, a0, pred, pA, c1, c0, target, pB, 0);
    skel_iter<<<grd, blk, 0, stream>>>(a0, a1, pred, pA, c0, c1, target, pB, 0);
    skel_iter<<<grd, blk, 0, stream>>>(a1, a0, pred, pA, c1, c0, target, pB, 1);
    finalize_kernel<<<1, 256, 0, stream>>>(pA, pB, out, NPART);
  } else {
    float* b0 = (float*)d_ws;
    float* b1 = b0 + NT;
    double* pA = (double*)(b1 + NT);
    double* pB = pA + 2 * NPART;
    const dim3 grd(NGY, NCH, B);       // chain = 0 only, 768 blocks
    skel_iter<<<grd, blk, 0, stream>>>(target, b0, pred, pA, nullptr, nullptr, nullptr, nullptr, 0);
    skel_iter<<<grd, blk, 0, stream>>>(b0, b1, pred, pA, nullptr, nullptr, nullptr, nullptr, 0);
    skel_iter<<<grd, blk, 0, stream>>>(b1, b0, pred, pA, nullptr, nullptr, nullptr, nullptr, 0);
    skel_iter<<<grd, blk, 0, stream>>>(b0, b1, pred, pA, nullptr, nullptr, nullptr, nullptr, 0);
    skel_iter<<<grd, blk, 0, stream>>>(b1, b0, pred, pA, nullptr, nullptr, nullptr, nullptr, 1);
    skel_iter<<<grd, blk, 0, stream>>>(pred, b0, target, pB, nullptr, nullptr, nullptr, nullptr, 0);
    skel_iter<<<grd, blk, 0, stream>>>(b0, b1, target, pB, nullptr, nullptr, nullptr, nullptr, 0);
    skel_iter<<<grd, blk, 0, stream>>>(b1, b0, target, pB, nullptr, nullptr, nullptr, nullptr, 0);
    skel_iter<<<grd, blk, 0, stream>>>(b0, b1, target, pB, nullptr, nullptr, nullptr, nullptr, 0);
    skel_iter<<<grd, blk, 0, stream>>>(b1, b0, target, pB, nullptr, nullptr, nullptr, nullptr, 1);
    finalize_kernel<<<1, 256, 0, stream>>>(pA, pB, out, NPART);
  }
}

// Round 6
// 385.203 us; speedup vs baseline: 3.6065x; 3.6065x over previous
//
#include <hip/hip_runtime.h>
#include <cfloat>

// ClDiceLoss (B=2, C=1, 192^3) fp32 — register-streaming soft-skeletonize.
//
// Round-13. Round-12 post-mortem: VGPR=40 + WRITE 424MB (and round-9:
// VGPR=40, WRITE 299MB) = SCRATCH SPILL, caused by the compile-time VGPR
// cap of launch_bounds(256,6) (85) vs the sched_barrier-pinned ring (~75
// live floats). Round-9's fetch explosion was the same spill, not XCD
// placement. Occupancy is set at runtime by actual VGPR (512/60 -> 8
// waves/SIMD allowed); rounds 10/11 were stuck at 3 waves/SIMD only
// because CZ=48 supplies just 3072 waves. Fix:
//   - CZ=24: 1536 blocks = 6 blocks/CU of real TLP.
//   - launch_bounds(256,4): cap 128, loose; compiler lands ~60 VGPR.
//   - NO sched_barrier pins (they force ring liveness -> pressure).
//   - keep bijective XCD swizzle (proven 120->64MB fetch at CZ=48).
// No-spill tells: VGPR=60, WRITE=110.6MB. Falsified by VGPR~40/WRITE>150.
//
// Decomposition: W = 192 = 64 lanes x 3 cols -> one wave spans full x;
// wave owns y-row gy; rows gy-2..gy+2 per plane; ring-5 z-stream (compiler
// may collapse to load-at-use — acceptable at 6 waves/SIMD).
// Boundaries: x edge == wave edge -> cndmask pads; y edge -> -FLT_MAX M
// rows; z edge -> zlo/zhi guards; clamped dup loads are min-neutral.
// No __shared__, no __syncthreads in skel_iter.

constexpr int D = 192, H = 192, W = 192, B = 2;
constexpr int HW = H * W;
constexpr int VOL = D * HW;
constexpr int CZ = 24;              // z-chunk (divides D)
constexpr int NCH = D / CZ;         // 8 chunks
constexpr int WPB = 4;              // waves (y-strips) per block
constexpr int NGY = H / WPB;        // 48
constexpr int STEPS = 30;           // 5-phase ring; emit window s in [3,CZ+2]
constexpr int NPART = B * NCH * H;  // 3072 per chain

struct F3 { float x, y, z; };       // 12B -> global_load_dwordx3

__device__ __forceinline__ float min3f(float a, float b, float c) {
  return fminf(fminf(a, b), c);
}
__device__ __forceinline__ float max3f(float a, float b, float c) {
  return fmaxf(fmaxf(a, b), c);
}

__global__ __launch_bounds__(256, 4) void skel_iter(
    const float* __restrict__ srcA, float* __restrict__ dstA,
    const float* __restrict__ othA, double* __restrict__ partA,
    const float* __restrict__ srcB, float* __restrict__ dstB,
    const float* __restrict__ othB, double* __restrict__ partB,
    int last) {
  const int tid = threadIdx.x;
  const int lane = tid & 63;
  const int wv = tid >> 6;

  // ---- XCD-locality swizzle (bijective: nwg % 8 == 0) ----
  // Each XCD receives a contiguous run of remapped ids = whole
  // (chunk,b,chain) windows with all 48 gy-groups -> halo re-reads are
  // local-L2 hits.
  const int nwg = gridDim.x * gridDim.y * gridDim.z;
  int wid = blockIdx.x + gridDim.x * (blockIdx.y + gridDim.y * blockIdx.z);
  wid = (wid & 7) * (nwg >> 3) + (wid >> 3);
  const int gyg = wid % NGY;
  const int combo = wid / NGY;
  const int chunk = combo % NCH;
  const int bz = combo / NCH;
  const int b = bz % B;
  const int chain = bz / B;

  const int gy = gyg * WPB + wv;            // strip row 0..191

  const float* __restrict__ vs = (chain ? srcB : srcA) + (size_t)b * VOL;
  float* __restrict__ vd = (chain ? dstB : dstA) + (size_t)b * VOL;
  const float* __restrict__ vo = (chain ? othB : othA) + (size_t)b * VOL;
  double* __restrict__ part = chain ? partB : partA;

  const int z0 = chunk * CZ;
  const int c0 = 3 * lane;

  // Row offsets (z-invariant), rows gy-2..gy+2 clamped (dup is min-neutral;
  // out-of-volume M rows masked below).
  int rb[5];
  #pragma unroll
  for (int r = 0; r < 5; ++r) rb[r] = min(max(gy - 2 + r, 0), H - 1) * W + c0;
  const bool ytop = (gy == 0), ybot = (gy == H - 1);
  const bool l0 = (lane == 0), l63 = (lane == 63);

  // Register state. Ring slot of plane q is (q - z0) mod 5; all slot
  // indices below are compile-time via the 5-phase unroll.
  float xa[5][5][3];     // x plane ring
  float Mprev[3];        // M(z-2), center row (for out)
  float h1[3], h2[3];    // hxy(z-2), hxy(z-3)
  float sp = 0.0f, ss = 0.0f;

  // Prologue: z0-2 -> slot 3, z0-1 -> slot 4, z0 -> slot 0.
  {
    const float* ps = vs + (size_t)max(z0 - 2, 0) * HW;
    #pragma unroll
    for (int r = 0; r < 5; ++r) {
      const F3 v = *(const F3*)(ps + rb[r]);
      xa[3][r][0] = v.x; xa[3][r][1] = v.y; xa[3][r][2] = v.z;
    }
    ps = vs + (size_t)max(z0 - 1, 0) * HW;
    #pragma unroll
    for (int r = 0; r < 5; ++r) {
      const F3 v = *(const F3*)(ps + rb[r]);
      xa[4][r][0] = v.x; xa[4][r][1] = v.y; xa[4][r][2] = v.z;
    }
    ps = vs + (size_t)z0 * HW;
    #pragma unroll
    for (int r = 0; r < 5; ++r) {
      const F3 v = *(const F3*)(ps + rb[r]);
      xa[0][r][0] = v.x; xa[0][r][1] = v.y; xa[0][r][2] = v.z;
    }
  }

  #pragma unroll 1
  for (int s5 = 0; s5 < STEPS; s5 += 5) {
    #pragma unroll
    for (int p = 0; p < 5; ++p) {
      const int s = s5 + p;
      const int z = z0 - 1 + s;                 // pipeline front
      const int LD  = (p + 1) % 5;              // plane z+2 (load target)
      const int SM2 = (p + 2) % 5;              // plane z-2
      const int SM1 = (p + 3) % 5;              // plane z-1 (M center)
      const int SC  = (p + 4) % 5;              // plane z

      // Issue plane z+2 (compiler may sink to use; OK at 6 waves/SIMD).
      {
        const int zc = min(z + 2, D - 1);
        const float* ps = vs + (size_t)zc * HW;
        #pragma unroll
        for (int r = 0; r < 5; ++r) {
          const F3 v = *(const F3*)(ps + rb[r]);
          xa[LD][r][0] = v.x; xa[LD][r][1] = v.y; xa[LD][r][2] = v.z;
        }
      }
      // Weight row for the fused reduction (last iteration only).
      const int zo = z - 2;
      const bool emit = (s >= 3) && (s <= CZ + 2);
      float w0 = 0.f, w1 = 0.f, w2 = 0.f;
      if (last && emit) {
        const F3 wv3 = *(const F3*)(vo + (size_t)zo * HW + rb[2]);
        w0 = wv3.x; w1 = wv3.y; w2 = wv3.z;
      }

      // ---- M(z-1): 7-pt cross min, rows gy-1..gy+1 (M rows 0..2) ----
      float xl[3], xr[3];
      #pragma unroll
      for (int r = 0; r < 3; ++r) {
        xl[r] = __shfl_up(xa[SM1][r + 1][2], 1, 64);    // col 3l-1
        xr[r] = __shfl_down(xa[SM1][r + 1][0], 1, 64);  // col 3l+3
        if (l0) xl[r] = FLT_MAX;    // x = -1  -> +inf pad (min-neutral)
        if (l63) xr[r] = FLT_MAX;   // x = 192 -> +inf pad
      }
      float Mc[3][3];
      #pragma unroll
      for (int r = 0; r < 3; ++r) {
        #pragma unroll
        for (int c = 0; c < 3; ++c) {
          const float le = (c == 0) ? xl[r] : xa[SM1][r + 1][c - 1];
          const float ri = (c == 2) ? xr[r] : xa[SM1][r + 1][c + 1];
          float v = min3f(xa[SM1][r + 1][c], le, ri);
          v = min3f(v, xa[SM1][r][c], xa[SM1][r + 2][c]);      // y+-1
          v = min3f(v, xa[SM2][r + 1][c], xa[SC][r + 1][c]);   // z+-1
          Mc[r][c] = v;
        }
      }
      // Out-of-volume M rows -> -inf (exact reduce_window -inf-pad for P).
      if (ytop) { Mc[0][0] = Mc[0][1] = Mc[0][2] = -FLT_MAX; }
      if (ybot) { Mc[2][0] = Mc[2][1] = Mc[2][2] = -FLT_MAX; }

      // ---- hxy(z-1): separable 3x3 max — row-max, then 2 shfls ----
      float rm[3];
      #pragma unroll
      for (int c = 0; c < 3; ++c) rm[c] = max3f(Mc[0][c], Mc[1][c], Mc[2][c]);
      float ml = __shfl_up(rm[2], 1, 64);
      float mr = __shfl_down(rm[0], 1, 64);
      if (l0) ml = -FLT_MAX;
      if (l63) mr = -FLT_MAX;
      float h0c[3];
      h0c[0] = max3f(ml, rm[0], rm[1]);
      h0c[1] = max3f(rm[0], rm[1], rm[2]);
      h0c[2] = max3f(rm[1], rm[2], mr);

      // ---- out(z-2) = relu(x - relu(P - M)) ----
      if (emit) {
        const bool zlo = (zo > 0), zhi = (zo < D - 1);
        float o[3];
        #pragma unroll
        for (int c = 0; c < 3; ++c) {
          float P = h1[c];
          if (zlo) P = fmaxf(P, h2[c]);
          if (zhi) P = fmaxf(P, h0c[c]);
          const float contour = fmaxf(P - Mprev[c], 0.0f);
          o[c] = fmaxf(xa[SM2][2][c] - contour, 0.0f);
        }
        if (last) {
          sp += o[0] * w0 + o[1] * w1 + o[2] * w2;
          ss += o[0] + o[1] + o[2];
        } else {
          *(F3*)(vd + (size_t)zo * HW + rb[2]) = {o[0], o[1], o[2]};
        }
      }

      // Ring advance (static names; compiler renames across phases).
      #pragma unroll
      for (int c = 0; c < 3; ++c) {
        h2[c] = h1[c];
        h1[c] = h0c[c];
        Mprev[c] = Mc[1][c];
      }
    }
  }

  if (last) {
    #pragma unroll
    for (int off = 32; off > 0; off >>= 1) {
      sp += __shfl_down(sp, off, 64);
      ss += __shfl_down(ss, off, 64);
    }
    if (lane == 0) {
      const int lin = (b * NCH + chunk) * H + gy;
      part[2 * lin] = (double)sp;
      part[2 * lin + 1] = (double)ss;
    }
  }
}

__global__ void finalize_kernel(const double* __restrict__ pa,
                                const double* __restrict__ pb,
                                float* __restrict__ out, int npart) {
  __shared__ double red[4][4];
  double s[4] = {0, 0, 0, 0};
  for (int i = threadIdx.x; i < npart; i += 256) {
    s[0] += pa[2 * i];
    s[1] += pa[2 * i + 1];
    s[2] += pb[2 * i];
    s[3] += pb[2 * i + 1];
  }
  #pragma unroll
  for (int off = 32; off > 0; off >>= 1)
    #pragma unroll
    for (int j = 0; j < 4; ++j) s[j] += __shfl_down(s[j], off, 64);
  const int wave = threadIdx.x >> 6, lane = threadIdx.x & 63;
  if (lane == 0)
    for (int j = 0; j < 4; ++j) red[j][wave] = s[j];
  __syncthreads();
  if (threadIdx.x == 0) {
    double t[4];
    for (int j = 0; j < 4; ++j)
      t[j] = red[j][0] + red[j][1] + red[j][2] + red[j][3];
    const double recall = (t[0] + 1e-12) / (t[1] + 1e-12);
    const double accv = (t[2] + 1e-12) / (t[3] + 1e-12);
    const double cldice = 2.0 * recall * accv / (recall + accv);
    out[0] = (float)(1.0 - cldice);
  }
}

extern "C" void kernel_launch(void* const* d_in, const int* in_sizes, int n_in,
                              void* d_out, int out_size, void* d_ws, size_t ws_size,
                              hipStream_t stream) {
  const float* pred = (const float*)d_in[0];
  const float* target = (const float*)d_in[1];
  float* out = (float*)d_out;
  const size_t NT = (size_t)VOL * B;

  const dim3 blk(256, 1, 1);
  const size_t need_merged = 4 * NT * sizeof(float) + 4 * NPART * sizeof(double);

  if (ws_size >= need_merged) {
    float* a0 = (float*)d_ws;
    float* a1 = a0 + NT;
    float* c0 = a1 + NT;
    float* c1 = c0 + NT;
    double* pA = (double*)(c1 + NT);
    double* pB = pA + 2 * NPART;
    const dim3 grd(NGY, NCH, 2 * B);   // 1536 blocks = 6 blocks/CU
    skel_iter<<<grd, blk, 0, stream>>>(target, a0, pred, pA, pred, c0, target, pB, 0);
    skel_iter<<<grd, blk, 0, stream>>>(a0, a1, pred, pA, c0, c1, target, pB, 0);
    skel_iter<<<grd, blk, 0, stream>>>(a1, a0, pred, pA, c1, c0, target, pB, 0);
    skel_iter<<<grd, blk, 0, stream>>>(a0, a1, pred, pA, c0, c1, target, pB, 0);
    skel_iter<<<grd, blk, 0, stream>>>(a1, a0, pred, pA, c1, c0, target, pB, 1);
    finalize_kernel<<<1, 256, 0, stream>>>(pA, pB, out, NPART);
  } else {
    float* b0 = (float*)d_ws;
    float* b1 = b0 + NT;
    double* pA = (double*)(b1 + NT);
    double* pB = pA + 2 * NPART;
    const dim3 grd(NGY, NCH, B);       // chain = 0 only, 768 blocks
    skel_iter<<<grd, blk, 0, stream>>>(target, b0, pred, pA, nullptr, nullptr, nullptr, nullptr, 0);
    skel_iter<<<grd, blk, 0, stream>>>(b0, b1, pred, pA, nullptr, nullptr, nullptr, nullptr, 0);
    skel_iter<<<grd, blk, 0, stream>>>(b1, b0, pred, pA, nullptr, nullptr, nullptr, nullptr, 0);
    skel_iter<<<grd, blk, 0, stream>>>(b0, b1, pred, pA, nullptr, nullptr, nullptr, nullptr, 0);
    skel_iter<<<grd, blk, 0, stream>>>(b1, b0, pred, pA, nullptr, nullptr, nullptr, nullptr, 1);
    skel_iter<<<grd, blk, 0, stream>>>(pred, b0, target, pB, nullptr, nullptr, nullptr, nullptr, 0);
    skel_iter<<<grd, blk, 0, stream>>>(b0, b1, target, pB, nullptr, nullptr, nullptr, nullptr, 0);
    skel_iter<<<grd, blk, 0, stream>>>(b1, b0, target, pB, nullptr, nullptr, nullptr, nullptr, 0);
    skel_iter<<<grd, blk, 0, stream>>>(b0, b1, target, pB, nullptr, nullptr, nullptr, nullptr, 0);
    skel_iter<<<grd, blk, 0, stream>>>(b1, b0, target, pB, nullptr, nullptr, nullptr, nullptr, 1);
    finalize_kernel<<<1, 256, 0, stream>>>(pA, pB, out, NPART);
  }
}